// Round 4
// baseline (883.744 us; speedup 1.0000x reference)
//
#include <hip/hip_runtime.h>

#define N_NODES 50000
#define DIM 128
#define BN_EPS 1e-5f

// ===========================================================================
// CSR build (once per call; graph identical across the 3 layers)
// ===========================================================================
__global__ __launch_bounds__(256) void edge_hist(const int* __restrict__ dst,
                                                 int* __restrict__ cnt, int E) {
  const int e = blockIdx.x * blockDim.x + threadIdx.x;
  if (e < E) atomicAdd(&cnt[dst[e]], 1);
}

__global__ __launch_bounds__(1024) void edge_scan(const int* __restrict__ cnt,
                                                  int* __restrict__ row_ptr) {
  __shared__ int part[1024];
  const int tid = threadIdx.x;
  const int per = (N_NODES + 1023) / 1024;  // 49
  const int start = tid * per;
  const int end = min(start + per, N_NODES);
  int s = 0;
  for (int i = start; i < end; ++i) s += cnt[i];
  part[tid] = s;
  __syncthreads();
  for (int off = 1; off < 1024; off <<= 1) {
    const int v = part[tid];
    const int u = (tid >= off) ? part[tid - off] : 0;
    __syncthreads();
    part[tid] = v + u;
    __syncthreads();
  }
  int run = (tid == 0) ? 0 : part[tid - 1];
  for (int i = start; i < end; ++i) {
    row_ptr[i] = run;
    run += cnt[i];
  }
  if (tid == 1023) row_ptr[N_NODES] = run;
}

__global__ __launch_bounds__(256) void edge_fill(const int* __restrict__ src,
                                                 const int* __restrict__ dst,
                                                 const int* __restrict__ row_ptr,
                                                 int* __restrict__ cur,
                                                 int* __restrict__ srcl, int E) {
  const int e = blockIdx.x * blockDim.x + threadIdx.x;
  if (e < E) {
    const int d = dst[e];
    const int pos = row_ptr[d] + atomicAdd(&cur[d], 1);
    srcl[pos] = src[e];
  }
}

// ===========================================================================
// Aggregation fused with GIN combine and (FUSE=1) the PREVIOUS layer's
// outer-BN + ReLU:  u = FUSE ? relu(a[c]*t + c[c]) : t
//   z[i] = (1+eps)*u[i] + sum_{j in nbrs(i)} relu(u[j])   (relu(u)=u if FUSE)
// One wave per node; lane owns 2 columns. No atomics, no barriers.
// ===========================================================================
template <int FUSE>
__global__ __launch_bounds__(256) void aggregate_combine(
    const float* __restrict__ h, const int* __restrict__ rp,
    const int* __restrict__ srcl, const float* __restrict__ eps_l,
    const float* __restrict__ ac, float* __restrict__ z) {
  const int node =
      __builtin_amdgcn_readfirstlane(blockIdx.x * 4 + (threadIdx.x >> 6));
  if (node >= N_NODES) return;
  const int lane = threadIdx.x & 63;
  const int col = lane * 2;

  float2 av, cv;
  if (FUSE) {
    av.x = ac[col]; av.y = ac[col + 1];
    cv.x = ac[DIM + col]; cv.y = ac[DIM + col + 1];
  }
  const float epsv = 1.0f + *eps_l;

  float2 acc;
  {
    const float2 u =
        *reinterpret_cast<const float2*>(h + (size_t)node * DIM + col);
    float2 s;
    if (FUSE) {
      s.x = fmaxf(fmaf(av.x, u.x, cv.x), 0.f);
      s.y = fmaxf(fmaf(av.y, u.y, cv.y), 0.f);
    } else {
      s = u;  // layer 0 self term: raw x (no relu on self)
    }
    acc.x = epsv * s.x;
    acc.y = epsv * s.y;
  }

  int p = rp[node];
  const int pe = rp[node + 1];
  for (; p + 8 <= pe; p += 8) {
    int s[8];
#pragma unroll
    for (int i = 0; i < 8; ++i) s[i] = srcl[p + i];
    float2 v[8];
#pragma unroll
    for (int i = 0; i < 8; ++i)
      v[i] = *reinterpret_cast<const float2*>(h + (size_t)s[i] * DIM + col);
#pragma unroll
    for (int i = 0; i < 8; ++i) {
      float mx, my;
      if (FUSE) {
        mx = fmaxf(fmaf(av.x, v[i].x, cv.x), 0.f);
        my = fmaxf(fmaf(av.y, v[i].y, cv.y), 0.f);
      } else {
        mx = fmaxf(v[i].x, 0.f);
        my = fmaxf(v[i].y, 0.f);
      }
      acc.x += mx;
      acc.y += my;
    }
  }
  for (; p < pe; ++p) {
    const int s = srcl[p];
    const float2 v =
        *reinterpret_cast<const float2*>(h + (size_t)s * DIM + col);
    if (FUSE) {
      acc.x += fmaxf(fmaf(av.x, v.x, cv.x), 0.f);
      acc.y += fmaxf(fmaf(av.y, v.y, cv.y), 0.f);
    } else {
      acc.x += fmaxf(v.x, 0.f);
      acc.y += fmaxf(v.y, 0.f);
    }
  }
  *reinterpret_cast<float2*>(z + (size_t)node * DIM + col) = acc;
}

// ===========================================================================
// Barrier-free GEMM, lane<->row, W via scalar (SGPR) broadcast.
//   out[r][j] = sum_k f(in[r][k]) * W[k][j] + bias[j]
//   MODE 2: f = identity;  MODE 1: f = relu(a[k]*x + c[k])
// Wave task: 64 rows (lane<->row) x 32 cols (col quarter = wave id in block).
// Epilogue: in-register butterfly reduces per-column sum AND sumsq with zero
// extra VGPR peak (squares formed at the first exchange), then one 64-lane
// atomic pair per wave into stats[].
// ===========================================================================
template <int MODE>
__global__ __launch_bounds__(256) void gemm_rw(
    const float* __restrict__ in, const float* __restrict__ ac,
    const float* __restrict__ W, const float* __restrict__ bias,
    float* __restrict__ out, float* __restrict__ stats) {
  const int lane = threadIdx.x & 63;
  const int colb = __builtin_amdgcn_readfirstlane((threadIdx.x >> 6) * 32);
  const int row = blockIdx.x * 64 + lane;
  const bool valid = row < N_NODES;
  const float* __restrict__ zr = in + (size_t)(valid ? row : 0) * DIM;

  float acc[32];
#pragma unroll
  for (int j = 0; j < 32; ++j) acc[j] = 0.f;

#define LDCH(Z0, Z1, CH)                                                    \
  {                                                                         \
    const int kb_ = (CH) * 8;                                               \
    Z0 = *reinterpret_cast<const float4*>(zr + kb_);                        \
    Z1 = *reinterpret_cast<const float4*>(zr + kb_ + 4);                    \
    if (MODE == 1) {                                                        \
      const float4 A0_ = *reinterpret_cast<const float4*>(ac + kb_);        \
      const float4 A1_ = *reinterpret_cast<const float4*>(ac + kb_ + 4);    \
      const float4 C0_ = *reinterpret_cast<const float4*>(ac + DIM + kb_);  \
      const float4 C1_ = *reinterpret_cast<const float4*>(ac + DIM + kb_ + 4); \
      Z0.x = fmaxf(fmaf(A0_.x, Z0.x, C0_.x), 0.f);                          \
      Z0.y = fmaxf(fmaf(A0_.y, Z0.y, C0_.y), 0.f);                          \
      Z0.z = fmaxf(fmaf(A0_.z, Z0.z, C0_.z), 0.f);                          \
      Z0.w = fmaxf(fmaf(A0_.w, Z0.w, C0_.w), 0.f);                          \
      Z1.x = fmaxf(fmaf(A1_.x, Z1.x, C1_.x), 0.f);                          \
      Z1.y = fmaxf(fmaf(A1_.y, Z1.y, C1_.y), 0.f);                          \
      Z1.z = fmaxf(fmaf(A1_.z, Z1.z, C1_.z), 0.f);                          \
      Z1.w = fmaxf(fmaf(A1_.w, Z1.w, C1_.w), 0.f);                          \
    }                                                                       \
  }

#define FMAK(ZK, KG)                                                        \
  {                                                                         \
    const float* __restrict__ wk_ = W + (size_t)(KG)*DIM + colb;            \
    _Pragma("unroll") for (int j = 0; j < 32; ++j) acc[j] =                 \
        fmaf(wk_[j], (ZK), acc[j]);                                         \
  }

#define FMACH(Z0, Z1, CH)                                                   \
  {                                                                         \
    const int kb0_ = (CH) * 8;                                              \
    FMAK(Z0.x, kb0_ + 0) FMAK(Z0.y, kb0_ + 1)                               \
    FMAK(Z0.z, kb0_ + 2) FMAK(Z0.w, kb0_ + 3)                               \
    FMAK(Z1.x, kb0_ + 4) FMAK(Z1.y, kb0_ + 5)                               \
    FMAK(Z1.z, kb0_ + 6) FMAK(Z1.w, kb0_ + 7)                               \
  }

  float4 a0, a1, b0, b1;
  LDCH(a0, a1, 0)
#pragma unroll 1
  for (int c = 0; c < 16; c += 2) {
    LDCH(b0, b1, c + 1)
    FMACH(a0, a1, c)
    if (c + 2 < 16) LDCH(a0, a1, c + 2)
    FMACH(b0, b1, c + 1)
  }
#undef LDCH
#undef FMAK
#undef FMACH

  // ---- epilogue: bias, store, fused sum/sumsq butterfly, atomics
  const float* __restrict__ bb = bias + colb;
  float v[32];
#pragma unroll
  for (int j = 0; j < 32; ++j) v[j] = valid ? (acc[j] + bb[j]) : 0.f;
  if (valid) {
    float* op = out + (size_t)row * DIM + colb;
#pragma unroll
    for (int j4 = 0; j4 < 8; ++j4) {
      float4 o;
      o.x = v[j4 * 4 + 0]; o.y = v[j4 * 4 + 1];
      o.z = v[j4 * 4 + 2]; o.w = v[j4 * 4 + 3];
      *reinterpret_cast<float4*>(op + j4 * 4) = o;
    }
  }
  // step o=32: 32 -> 16 values; squares formed here (before any additions)
  float q[16];
#pragma unroll
  for (int jj = 0; jj < 16; ++jj) {
    const bool hi = (lane & 32) != 0;
    const float keep = hi ? v[jj + 16] : v[jj];
    const float send = hi ? v[jj] : v[jj + 16];
    const float recv = __shfl_xor(send, 32);
    v[jj] = keep + recv;
    q[jj] = keep * keep + recv * recv;
  }
#define RSTEP(ARR, CNT, O)                                                  \
  {                                                                         \
    _Pragma("unroll") for (int jj = 0; jj < (CNT); ++jj) {                  \
      const bool hi_ = (lane & (O)) != 0;                                   \
      const float keep_ = hi_ ? ARR[jj + (CNT)] : ARR[jj];                  \
      const float send_ = hi_ ? ARR[jj] : ARR[jj + (CNT)];                  \
      ARR[jj] = keep_ + __shfl_xor(send_, (O));                             \
    }                                                                       \
  }
  RSTEP(v, 8, 16) RSTEP(q, 8, 16)
  RSTEP(v, 4, 8)  RSTEP(q, 4, 8)
  RSTEP(v, 2, 4)  RSTEP(q, 2, 4)
  RSTEP(v, 1, 2)  RSTEP(q, 1, 2)
#undef RSTEP
  v[0] += __shfl_xor(v[0], 1);
  q[0] += __shfl_xor(q[0], 1);
  if ((lane & 1) == 0) {  // lane l holds totals for column colb + (l>>1)
    const int jc = colb + (lane >> 1);
    atomicAdd(&stats[jc], v[0]);
    atomicAdd(&stats[DIM + jc], q[0]);
  }
}

// ---------------------------------------------------------------------------
// Fold (sum, sumsq) -> (a = g*rsqrt(var+eps), c = b - mu*a). One block.
// ---------------------------------------------------------------------------
__global__ void bn_param(const float* __restrict__ stats,
                         const float* __restrict__ g,
                         const float* __restrict__ b, float* __restrict__ ac) {
  const int j = threadIdx.x;
  const float invN = 1.0f / (float)N_NODES;
  const float mu = stats[j] * invN;
  const float var = stats[DIM + j] * invN - mu * mu;
  const float a = g[j] * rsqrtf(var + BN_EPS);
  ac[j] = a;
  ac[DIM + j] = b[j] - mu * a;
}

// ---------------------------------------------------------------------------
// Final output only: out = a[k]*t + c[k] (no relu).
// ---------------------------------------------------------------------------
__global__ __launch_bounds__(256) void apply_bn(const float* __restrict__ t,
                                                const float* __restrict__ ac,
                                                float* __restrict__ out) {
  const int i = blockIdx.x * blockDim.x + threadIdx.x;
  const int k = (i * 4) & (DIM - 1);
  const float4 v = *reinterpret_cast<const float4*>(&t[(size_t)i * 4]);
  const float4 a = *reinterpret_cast<const float4*>(&ac[k]);
  const float4 c = *reinterpret_cast<const float4*>(&ac[DIM + k]);
  float4 r;
  r.x = fmaf(a.x, v.x, c.x);
  r.y = fmaf(a.y, v.y, c.y);
  r.z = fmaf(a.z, v.z, c.z);
  r.w = fmaf(a.w, v.w, c.w);
  *reinterpret_cast<float4*>(&out[(size_t)i * 4]) = r;
}

extern "C" void kernel_launch(void* const* d_in, const int* in_sizes, int n_in,
                              void* d_out, int out_size, void* d_ws,
                              size_t ws_size, hipStream_t stream) {
  const float* x = (const float*)d_in[0];
  const int* ei = (const int*)d_in[1];  // [2][E]: src = ei, dst = ei+E
  const float* eps = (const float*)d_in[2];
  const float* W1 = (const float*)d_in[3];
  const float* b1 = (const float*)d_in[4];
  const float* g1 = (const float*)d_in[5];
  const float* bb1 = (const float*)d_in[6];
  const float* W2 = (const float*)d_in[7];
  const float* b2 = (const float*)d_in[8];
  const float* g2 = (const float*)d_in[9];
  const float* bb2 = (const float*)d_in[10];

  const int E = in_sizes[1] / 2;
  const size_t ND = (size_t)N_NODES * DIM;

  float* bufA = (float*)d_ws;
  float* bufB = bufA + ND;
  float* stats = bufB + ND;          // 512 floats
  float* bnp = stats + 512;          // 512 floats (a1,c1 | a2,c2)
  int* cnt = (int*)(bnp + 512);      // [N]
  int* row_ptr = cnt + N_NODES;      // [N+1]
  int* cur = row_ptr + N_NODES + 1;  // [N]
  int* srcl = cur + N_NODES;         // [E]

  const int edge_grid = (E + 255) / 256;
  const int agg_grid = (N_NODES + 3) / 4;          // 12500, exact
  const int gemm_grid = (N_NODES + 63) / 64;       // 782
  const int apply_grid = (N_NODES * DIM / 4) / 256;  // 6250, exact

  // ---- CSR build
  hipMemsetAsync(cnt, 0, sizeof(int) * (size_t)N_NODES, stream);
  hipMemsetAsync(cur, 0, sizeof(int) * (size_t)N_NODES, stream);
  edge_hist<<<edge_grid, 256, 0, stream>>>(ei + E, cnt, E);
  edge_scan<<<1, 1024, 0, stream>>>(cnt, row_ptr);
  edge_fill<<<edge_grid, 256, 0, stream>>>(ei, ei + E, row_ptr, cur, srcl, E);

  const float* hin = x;   // aggregate input (x, then t2 of previous layer)
  float* zb = bufA;       // aggregate out / gemm1 in; gemm2 out
  float* tb = bufB;       // gemm1 out / gemm2 in
  for (int l = 0; l < 3; ++l) {
    hipMemsetAsync(stats, 0, sizeof(float) * 512, stream);
    if (l == 0)
      aggregate_combine<0><<<agg_grid, 256, 0, stream>>>(hin, row_ptr, srcl,
                                                         eps + l, nullptr, zb);
    else
      aggregate_combine<1><<<agg_grid, 256, 0, stream>>>(
          hin, row_ptr, srcl, eps + l, bnp + 256, zb);
    gemm_rw<2><<<gemm_grid, 256, 0, stream>>>(
        zb, nullptr, W1 + (size_t)l * DIM * DIM, b1 + l * DIM, tb, stats);
    bn_param<<<1, DIM, 0, stream>>>(stats, g1 + l * DIM, bb1 + l * DIM, bnp);
    gemm_rw<1><<<gemm_grid, 256, 0, stream>>>(
        tb, bnp, W2 + (size_t)l * DIM * DIM, b2 + l * DIM, zb, stats + 256);
    bn_param<<<1, DIM, 0, stream>>>(stats + 256, g2 + l * DIM, bb2 + l * DIM,
                                    bnp + 256);
    hin = zb;           // this layer's t2
    float* tmp = zb;    // ping-pong so next aggregate never writes its input
    zb = tb;
    tb = tmp;
  }
  apply_bn<<<apply_grid, 256, 0, stream>>>(hin, bnp + 256, (float*)d_out);
}